// Round 4
// baseline (387.238 us; speedup 1.0000x reference)
//
#include <hip/hip_runtime.h>
#include <math.h>

// DynamicRelationModeler: x=concat(img,txt) [512x512]; per r: a=x@Wl_r^T, b=x@Wr_r^T;
// h=a_i+b_j+b1_r; LN over H; s=relu(hn)@w2_r+b2_r; argmax/max over r; mask.
//
// Score decomposition (exact): relu(z) = (z+|z|)/2, so with P=0.5*w2*gamma, Q=0.5*w2*beta:
//   s = sv*(PA'_i + PB'_j) + QS_r + sum_k sign(w2_k)*|t_k*P_k + Q_k| + b2_r
// where t_k = (a_ik + b_jk - mu)*sv. Inner loop = 4 VALU ops per (pair,k).
//
// R4: all GEMM-ish kernels are LDS-free — operands stream straight from
// global through L1/L2 (A-reads are 4-address broadcasts, B-reads hit 64B
// L1 lines 4x across consecutive k4 steps; uniform planes go via s_load).
//
// ws layout (floats):
//   Aarr [4][512][512], Barr [4][512][512] (b1 folded), dotp [2][4][512][512],
//   Spart[2][4][512][512], then small arrays (row stats, planes) at 24*PLANE.

namespace {
constexpr size_t PLANE  = 512 * 512;            // 262144
constexpr size_t OFF_A   = 0;
constexpr size_t OFF_B   = OFF_A + 4 * PLANE;
constexpr size_t OFF_DOT = OFF_B + 4 * PLANE;
constexpr size_t OFF_S   = OFF_DOT + 8 * PLANE;
constexpr size_t OFF_MA  = OFF_S + 8 * PLANE;   // 24*PLANE; MA,QA,PAp,MB,QB,PBp contiguous
constexpr size_t OFF_QA  = OFF_MA + 2048;
constexpr size_t OFF_PAp = OFF_QA + 2048;
constexpr size_t OFF_MB  = OFF_PAp + 2048;
constexpr size_t OFF_QB  = OFF_MB + 2048;
constexpr size_t OFF_PBp = OFF_QB + 2048;
constexpr size_t OFF_P   = OFF_PBp + 2048;      // P,Q,SG contiguous
constexpr size_t OFF_Q   = OFF_P + 2048;
constexpr size_t OFF_SG  = OFF_Q + 2048;
constexpr size_t OFF_QSP = OFF_SG + 2048;       // 8 floats
}

// ---------------- K0: input GEMM  C[n][4096] = x @ [Wl|Wr]^T (LDS-free) ------
// grid 512 = 8 it(64) x 64 col-tiles(64); block 256 (16tx x 16ty, 4x4 reg tile)
__global__ __launch_bounds__(256) void k0_gemm(const float* __restrict__ img,
                                               const float* __restrict__ txt,
                                               const float* __restrict__ W1,
                                               const float* __restrict__ b1,
                                               float* __restrict__ ws) {
  const int b = blockIdx.x;
  const int it = b >> 6;
  const int ct = b & 63;
  const int which = ct >> 5;
  const int r = (ct >> 3) & 3;
  const int ht = ct & 7;
  const int i0 = it << 6, h0 = ht << 6;
  const int t = threadIdx.x;
  const int tx = t & 15, ty = t >> 4;

  const float* xr[4];
#pragma unroll
  for (int c = 0; c < 4; ++c) {
    const int xi = i0 + 4 * ty + c;
    xr[c] = (xi < 256) ? (img + (size_t)xi * 512)
                       : (txt + (size_t)(xi - 256) * 512);
  }
  const float* wr[4];
#pragma unroll
  for (int d = 0; d < 4; ++d)
    wr[d] = W1 + (size_t)(r * 512 + h0 + 4 * tx + d) * 1024 + which * 512;

  float acc[16];
#pragma unroll
  for (int p = 0; p < 16; ++p) acc[p] = 0.f;

  for (int kc = 0; kc < 8; ++kc) {   // 8 chunks of 64 k; chunked accumulation
    float pacc[16];
#pragma unroll
    for (int p = 0; p < 16; ++p) pacc[p] = 0.f;
#pragma unroll 2
    for (int k4 = 0; k4 < 16; ++k4) {
      const int kk = (kc << 6) + (k4 << 2);
      float4 xv[4], wv[4];
#pragma unroll
      for (int c = 0; c < 4; ++c) xv[c] = *(const float4*)(xr[c] + kk);
#pragma unroll
      for (int d = 0; d < 4; ++d) wv[d] = *(const float4*)(wr[d] + kk);
#pragma unroll
      for (int e = 0; e < 4; ++e) {
        float xa[4], wa[4];
#pragma unroll
        for (int c = 0; c < 4; ++c) xa[c] = ((const float*)&xv[c])[e];
#pragma unroll
        for (int d = 0; d < 4; ++d) wa[d] = ((const float*)&wv[d])[e];
#pragma unroll
        for (int c = 0; c < 4; ++c)
#pragma unroll
          for (int d = 0; d < 4; ++d)
            pacc[c * 4 + d] = fmaf(xa[c], wa[d], pacc[c * 4 + d]);
      }
    }
#pragma unroll
    for (int p = 0; p < 16; ++p) acc[p] += pacc[p];
  }

  float4 bb = make_float4(0.f, 0.f, 0.f, 0.f);
  if (which) bb = *(const float4*)(b1 + r * 512 + h0 + 4 * tx);
  float* dst = ws + (which ? OFF_B : OFF_A) + (size_t)r * PLANE;
#pragma unroll
  for (int c = 0; c < 4; ++c) {
    float4 v;
    v.x = acc[c * 4 + 0] + bb.x;
    v.y = acc[c * 4 + 1] + bb.y;
    v.z = acc[c * 4 + 2] + bb.z;
    v.w = acc[c * 4 + 3] + bb.w;
    *(float4*)(dst + (size_t)(i0 + 4 * ty + c) * 512 + h0 + 4 * tx) = v;
  }
}

// ---------------- K1: row stats + weighted row sums + planes ----------------
__global__ __launch_bounds__(256) void k1_stats(float* __restrict__ ws,
                                                const float* __restrict__ gamma,
                                                const float* __restrict__ beta,
                                                const float* __restrict__ w2) {
  __shared__ float red[4];
  const int t = threadIdx.x;
  const int gw = (blockIdx.x * 256 + t) >> 6;
  const int lane = t & 63;
  const int which = gw >> 11;
  const int rr = (gw >> 9) & 3;
  const int row = gw & 511;
  const float* src =
      ws + (which ? OFF_B : OFF_A) + (size_t)(rr * 512 + row) * 512 + lane * 8;
  const float* gp = gamma + rr * 512 + lane * 8;
  const float* wp = w2 + rr * 512 + lane * 8;
  float s = 0.f, q = 0.f, pa = 0.f, gg = 0.f;
#pragma unroll
  for (int c = 0; c < 2; ++c) {
    const float4 v = *(const float4*)(src + c * 4);
    const float4 g = *(const float4*)(gp + c * 4);
    const float4 w = *(const float4*)(wp + c * 4);
    const float vv[4] = {v.x, v.y, v.z, v.w};
    const float gv[4] = {g.x, g.y, g.z, g.w};
    const float wv[4] = {w.x, w.y, w.z, w.w};
#pragma unroll
    for (int e = 0; e < 4; ++e) {
      const float p = 0.5f * gv[e] * wv[e];
      s += vv[e];
      q += vv[e] * vv[e];
      pa += p * vv[e];
      gg += p;
    }
  }
#pragma unroll
  for (int off = 32; off >= 1; off >>= 1) {
    s += __shfl_down(s, off, 64);
    q += __shfl_down(q, off, 64);
    pa += __shfl_down(pa, off, 64);
    gg += __shfl_down(gg, off, 64);
  }
  if (lane == 0) {
    const float ma = s * (1.f / 512.f);
    ws[(which ? OFF_MB : OFF_MA) + rr * 512 + row] = ma;
    ws[(which ? OFF_QB : OFF_QA) + rr * 512 + row] = q;
    ws[(which ? OFF_PBp : OFF_PAp) + rr * 512 + row] = pa - ma * gg;
  }
  if (blockIdx.x < 8) {
    const int idx = blockIdx.x * 256 + t;  // r*512+k
    const float g = gamma[idx], be = beta[idx], w = w2[idx];
    const float qv = 0.5f * be * w;
    ws[OFF_P + idx] = 0.5f * g * w;
    ws[OFF_Q + idx] = qv;
    ws[OFF_SG + idx] = copysignf(1.f, w);
    float qs = qv;
#pragma unroll
    for (int off = 32; off >= 1; off >>= 1) qs += __shfl_down(qs, off, 64);
    if (lane == 0) red[t >> 6] = qs;
    __syncthreads();
    if (t == 0) ws[OFF_QSP + blockIdx.x] = red[0] + red[1] + red[2] + red[3];
  }
}

// ---------------- K2: pairwise dot (LDS-free) ----------------
// grid 512 = 8jt x 8it x 4r x 2ks; block 256 (16x16, 4x4 reg tile)
__global__ __launch_bounds__(256) void k2_dot(const float* __restrict__ wsA,
                                              const float* __restrict__ wsB,
                                              float* __restrict__ wsDot) {
  const int b = blockIdx.x;
  const int jt = b & 7, it = (b >> 3) & 7, r = (b >> 6) & 3, ks = b >> 8;
  const int i0 = it << 6, j0 = jt << 6;
  const int kb = ks << 8;
  const int t = threadIdx.x;
  const int tx = t & 15, ty = t >> 4;

  const float* ar[4];
  const float* br[4];
#pragma unroll
  for (int c = 0; c < 4; ++c)
    ar[c] = wsA + (size_t)(r * 512 + i0 + 4 * ty + c) * 512 + kb;
#pragma unroll
  for (int d = 0; d < 4; ++d)
    br[d] = wsB + (size_t)(r * 512 + j0 + 4 * tx + d) * 512 + kb;

  float acc[16];
#pragma unroll
  for (int p = 0; p < 16; ++p) acc[p] = 0.f;

  for (int kc = 0; kc < 4; ++kc) {   // 4 chunks of 64 k
    float pacc[16];
#pragma unroll
    for (int p = 0; p < 16; ++p) pacc[p] = 0.f;
#pragma unroll 2
    for (int k4 = 0; k4 < 16; ++k4) {
      const int kk = (kc << 6) + (k4 << 2);
      float4 av[4], bv[4];
#pragma unroll
      for (int c = 0; c < 4; ++c) av[c] = *(const float4*)(ar[c] + kk);
#pragma unroll
      for (int d = 0; d < 4; ++d) bv[d] = *(const float4*)(br[d] + kk);
#pragma unroll
      for (int e = 0; e < 4; ++e) {
        float aa[4], ba[4];
#pragma unroll
        for (int c = 0; c < 4; ++c) aa[c] = ((const float*)&av[c])[e];
#pragma unroll
        for (int d = 0; d < 4; ++d) ba[d] = ((const float*)&bv[d])[e];
#pragma unroll
        for (int c = 0; c < 4; ++c)
#pragma unroll
          for (int d = 0; d < 4; ++d)
            pacc[c * 4 + d] = fmaf(aa[c], ba[d], pacc[c * 4 + d]);
      }
    }
#pragma unroll
    for (int p = 0; p < 16; ++p) acc[p] += pacc[p];
  }

  float* dst = wsDot + (size_t)ks * (4 * PLANE) + (size_t)r * PLANE;
#pragma unroll
  for (int c = 0; c < 4; ++c) {
    float4 v;
    v.x = acc[c * 4 + 0]; v.y = acc[c * 4 + 1];
    v.z = acc[c * 4 + 2]; v.w = acc[c * 4 + 3];
    *(float4*)(dst + (size_t)(i0 + 4 * ty + c) * 512 + j0 + 4 * tx) = v;
  }
}

// ---------------- K3: score kernel (LDS-free, 4-op inner loop) ----------------
// grid 1024 = 16jt(32) x 8it(64) x 4r x 2ks; block 256 (16tx x 16ty; 4i x 2j)
// A-reads: 4-address wave broadcasts; B-reads: 16x16B (64B L1-line reuse x4);
// P/Q/S planes: block-uniform pointer -> s_load.
__global__ __launch_bounds__(256) void k3_score(const float* __restrict__ wsA,
                                                const float* __restrict__ wsB,
                                                const float* __restrict__ wsDot,
                                                const float* __restrict__ stats,
                                                const float* __restrict__ planes,
                                                float* __restrict__ sout) {
  const int b = blockIdx.x;
  const int jt = b & 15, it = (b >> 4) & 7, r = (b >> 7) & 3, ks = b >> 9;
  const int i0 = it << 6, j0 = jt << 5;
  const int t = threadIdx.x;
  const int tx = t & 15, ty = t >> 4;

  // stats region: MA+0, QA+2048, PAp+4096, MB+6144, QB+8192, PBp+10240
  const float4 mav = *(const float4*)(stats + 0 + r * 512 + i0 + 4 * ty);
  const float4 qav = *(const float4*)(stats + 2048 + r * 512 + i0 + 4 * ty);
  const float4 pav = *(const float4*)(stats + 4096 + r * 512 + i0 + 4 * ty);
  const float2 mbv = *(const float2*)(stats + 6144 + r * 512 + j0 + 2 * tx);
  const float2 qbv = *(const float2*)(stats + 8192 + r * 512 + j0 + 2 * tx);
  const float2 pbv = *(const float2*)(stats + 10240 + r * 512 + j0 + 2 * tx);
  const float maA[4] = {mav.x, mav.y, mav.z, mav.w};
  const float qaA[4] = {qav.x, qav.y, qav.z, qav.w};
  const float paA[4] = {pav.x, pav.y, pav.z, pav.w};
  const float mbA[2] = {mbv.x, mbv.y};
  const float qbA[2] = {qbv.x, qbv.y};
  const float pbA[2] = {pbv.x, pbv.y};

  float Sv[8], Tv[8], acc[8];
#pragma unroll
  for (int c = 0; c < 4; ++c) {
    const size_t doff =
        (size_t)r * PLANE + (size_t)(i0 + 4 * ty + c) * 512 + j0 + 2 * tx;
    const float2 d0 = *(const float2*)(wsDot + doff);
    const float2 d1 = *(const float2*)(wsDot + 4 * PLANE + doff);
    const float dA[2] = {d0.x + d1.x, d0.y + d1.y};
#pragma unroll
    for (int d = 0; d < 2; ++d) {
      const int p = c * 2 + d;
      const float mu = maA[c] + mbA[d];
      const float msq = (qaA[c] + qbA[d] + 2.f * dA[d]) * (1.f / 512.f);
      const float var = msq - mu * mu;
      const float sv = 1.0f / sqrtf(var + 1e-5f);  // precise (no fast-math)
      Sv[p] = sv;
      Tv[p] = -mu * sv;
      acc[p] = ks ? 0.f : sv * (paA[c] + pbA[d]);  // linear half (ks==0 only)
    }
  }

  const int kb = ks << 8;
  const float* ar[4];
  const float* br[2];
#pragma unroll
  for (int c = 0; c < 4; ++c)
    ar[c] = wsA + (size_t)(r * 512 + i0 + 4 * ty + c) * 512 + kb;
#pragma unroll
  for (int d = 0; d < 2; ++d)
    br[d] = wsB + (size_t)(r * 512 + j0 + 2 * tx + d) * 512 + kb;
  const float* pp = planes + r * 512 + kb;  // P+0, Q+2048, SG+4096 (uniform)

  for (int kc = 0; kc < 4; ++kc) {   // 4 chunks of 64 k; chunked accumulation
    float cacc[8];
#pragma unroll
    for (int p = 0; p < 8; ++p) cacc[p] = 0.f;
#pragma unroll 2
    for (int k4 = 0; k4 < 16; ++k4) {
      const int kk = (kc << 6) + (k4 << 2);
      float4 av[4], bv[2];
#pragma unroll
      for (int c = 0; c < 4; ++c) av[c] = *(const float4*)(ar[c] + kk);
#pragma unroll
      for (int d = 0; d < 2; ++d) bv[d] = *(const float4*)(br[d] + kk);
      const float4 Pk = *(const float4*)(pp + kk);
      const float4 Qk = *(const float4*)(pp + 2048 + kk);
      const float4 Sk = *(const float4*)(pp + 4096 + kk);
#pragma unroll
      for (int e = 0; e < 4; ++e) {
        const float pk = ((const float*)&Pk)[e];
        const float qk = ((const float*)&Qk)[e];
        const float sk = ((const float*)&Sk)[e];
        float aa[4], bb[2];
#pragma unroll
        for (int c = 0; c < 4; ++c) aa[c] = ((const float*)&av[c])[e];
#pragma unroll
        for (int d = 0; d < 2; ++d) bb[d] = ((const float*)&bv[d])[e];
#pragma unroll
        for (int c = 0; c < 4; ++c)
#pragma unroll
          for (int d = 0; d < 2; ++d) {
            const int p = c * 2 + d;
            const float u = aa[c] + bb[d];
            const float t1 = fmaf(u, Sv[p], Tv[p]);
            const float h = fmaf(t1, pk, qk);
            cacc[p] = fmaf(fabsf(h), sk, cacc[p]);  // abs = free VOP3 modifier
          }
      }
    }
#pragma unroll
    for (int p = 0; p < 8; ++p) acc[p] += cacc[p];
  }

  float* dst = sout + (size_t)ks * (4 * PLANE) + (size_t)r * PLANE;
#pragma unroll
  for (int c = 0; c < 4; ++c) {
    float2 v;
    v.x = acc[c * 2 + 0];
    v.y = acc[c * 2 + 1];
    *(float2*)(dst + (size_t)(i0 + 4 * ty + c) * 512 + j0 + 2 * tx) = v;
  }
}

// ---------------- K4: combine + outputs ----------------
__global__ __launch_bounds__(256) void k4_combine(const float* __restrict__ ws,
                                                  const float* __restrict__ img,
                                                  const float* __restrict__ txt,
                                                  const float* __restrict__ b2,
                                                  float* __restrict__ out) {
  const int idx = blockIdx.x * 256 + threadIdx.x;
  const int i = idx >> 9, j = idx & 511;
  const float* s0 = ws + OFF_S;
  const float* s1 = ws + OFF_S + 4 * PLANE;
  const float* qsp = ws + OFF_QSP;
  float best = -3.4e38f;
  int rel = 0;
#pragma unroll
  for (int r = 0; r < 4; ++r) {
    const float cr = b2[r] + qsp[2 * r] + qsp[2 * r + 1];
    const float s = s0[r * PLANE + idx] + s1[r * PLANE + idx] + cr;
    if (s > best) { best = s; rel = r; }  // strict > == first-index argmax
  }
  out[idx] = (i < 256) ? img[idx] : txt[idx - 131072];
  out[PLANE + idx] = best;
  out[2 * PLANE + idx] = (float)rel;
  out[3 * PLANE + idx] = (i != j && (double)best > 0.2) ? 1.0f : 0.0f;
}

extern "C" void kernel_launch(void* const* d_in, const int* in_sizes, int n_in,
                              void* d_out, int out_size, void* d_ws, size_t ws_size,
                              hipStream_t stream) {
  const float* img   = (const float*)d_in[0];
  const float* txt   = (const float*)d_in[1];
  const float* W1    = (const float*)d_in[2];
  const float* b1    = (const float*)d_in[3];
  const float* gamma = (const float*)d_in[4];
  const float* beta  = (const float*)d_in[5];
  const float* w2    = (const float*)d_in[6];
  const float* b2    = (const float*)d_in[7];
  float* ws  = (float*)d_ws;
  float* out = (float*)d_out;
  (void)in_sizes; (void)n_in; (void)out_size; (void)ws_size;

  hipLaunchKernelGGL(k0_gemm,    dim3(512),  dim3(256), 0, stream, img, txt, W1, b1, ws);
  hipLaunchKernelGGL(k1_stats,   dim3(1024), dim3(256), 0, stream, ws, gamma, beta, w2);
  hipLaunchKernelGGL(k2_dot,     dim3(512),  dim3(256), 0, stream,
                     ws + OFF_A, ws + OFF_B, ws + OFF_DOT);
  hipLaunchKernelGGL(k3_score,   dim3(1024), dim3(256), 0, stream,
                     ws + OFF_A, ws + OFF_B, ws + OFF_DOT,
                     ws + OFF_MA, ws + OFF_P, ws + OFF_S);
  hipLaunchKernelGGL(k4_combine, dim3(1024), dim3(256), 0, stream, ws, img, txt, b2, out);
}

// Round 5
// 245.870 us; speedup vs baseline: 1.5750x; 1.5750x over previous
//
#include <hip/hip_runtime.h>
#include <math.h>

// DynamicRelationModeler — R5 structure.
// Exact decomposition: relu(z)=(z+|z|)/2; P=w2*gamma/2, Q=w2*beta/2, S=sign(w2):
//   score = sv*(PA'_i+PB'_j) + QS_r + b2_r + sum_k S_k*|sv*(P_k*(a~+b~)) + Q_k|
// with a~ = a - mean_k(a_i), b~ = b+b1 - mean_k(b_j+b1) (K1 centers A/B in place),
// sv = rsqrt((Qa~_i + Qb~_j + 2*dot~_ij)/512 + eps).
// Inner loop: 3 VALU ops per (pair,k); P/Q/S via scalar loads; A-side from global
// (4-line broadcast reads); B-side staged in LDS (XOR-swizzled, 2-way max = free).
// K0 k-splits x2 into the DOT region (K1 sums partials); K2 overwrites DOT after.

namespace {
constexpr size_t PLANE  = 512 * 512;            // 262144
constexpr size_t OFF_A   = 0;
constexpr size_t OFF_B   = OFF_A + 4 * PLANE;
constexpr size_t OFF_DOT = OFF_B + 4 * PLANE;   // K0 k-partials, then K2 dots
constexpr size_t OFF_S   = OFF_DOT + 8 * PLANE;
constexpr size_t OFF_MA  = OFF_S + 8 * PLANE;   // stats block base
constexpr size_t OFF_QA  = OFF_MA + 2048;
constexpr size_t OFF_PAp = OFF_QA + 2048;
constexpr size_t OFF_MB  = OFF_PAp + 2048;
constexpr size_t OFF_QB  = OFF_MB + 2048;
constexpr size_t OFF_PBp = OFF_QB + 2048;
constexpr size_t OFF_P   = OFF_PBp + 2048;      // P,Q,SG contiguous
constexpr size_t OFF_Q   = OFF_P + 2048;
constexpr size_t OFF_SG  = OFF_Q + 2048;
constexpr size_t OFF_QSP = OFF_SG + 2048;       // 8 floats
}

__device__ __forceinline__ int swz(int row) { return (row + (row >> 2)) & 15; }

// ---------------- K0: input GEMM, k-split x2 ----------------
// grid 1024 = 4it(128) x 2which x 4r x 16ht(32) x 2ks; block 256 (16tx x 16ty)
// Pi=8 (rows ty+16c, global broadcast), Pj=2 (W rows 2tx+d, LDS-staged).
__global__ __launch_bounds__(256) void k0_gemm(const float* __restrict__ img,
                                               const float* __restrict__ txt,
                                               const float* __restrict__ W1,
                                               float* __restrict__ ws) {
  const int b = blockIdx.x;
  const int it = b >> 8;
  const int which = (b >> 7) & 1;
  const int r = (b >> 5) & 3;
  const int ht = (b >> 1) & 15;
  const int ks = b & 1;
  const int i0 = it << 7, h0 = ht << 5, kb0 = ks << 8;
  const int t = threadIdx.x, tx = t & 15, ty = t >> 4;

  __shared__ float Ws[32 * 64];   // 8 KB, row-major [h][k], 16B-chunk XOR swizzle

  const float* xp[8];
#pragma unroll
  for (int c = 0; c < 8; ++c) {
    const int xi = i0 + ty + 16 * c;
    xp[c] = (xi < 256 ? img + (size_t)xi * 512
                      : txt + (size_t)(xi - 256) * 512) + kb0;
  }
  const int wrow = t >> 3, wcol = t & 7;
  const int sww = swz(wrow);
  const float* wsrc = W1 + (size_t)(r * 512 + h0 + wrow) * 1024 + which * 512 + kb0;

  float acc[16];
#pragma unroll
  for (int p = 0; p < 16; ++p) acc[p] = 0.f;

  for (int kc = 0; kc < 4; ++kc) {      // 4 chunks of 64 k (256 k per ks-half)
    const int ko = kc << 6;
    const float4 w0 = *(const float4*)(wsrc + ko + 4 * wcol);
    const float4 w1 = *(const float4*)(wsrc + ko + 4 * (wcol + 8));
    __syncthreads();
    *(float4*)&Ws[wrow * 64 + ((wcol ^ sww) << 2)] = w0;
    *(float4*)&Ws[wrow * 64 + (((wcol + 8) ^ sww) << 2)] = w1;
    __syncthreads();
    float pacc[16];
#pragma unroll
    for (int p = 0; p < 16; ++p) pacc[p] = 0.f;
#pragma unroll 4
    for (int k4 = 0; k4 < 16; ++k4) {
      float4 av[8], wv[2];
#pragma unroll
      for (int c = 0; c < 8; ++c) av[c] = *(const float4*)(xp[c] + ko + 4 * k4);
#pragma unroll
      for (int d = 0; d < 2; ++d) {
        const int rw = 2 * tx + d;
        wv[d] = *(const float4*)&Ws[rw * 64 + ((k4 ^ swz(rw)) << 2)];
      }
#pragma unroll
      for (int kk = 0; kk < 4; ++kk)
#pragma unroll
        for (int c = 0; c < 8; ++c)
#pragma unroll
          for (int d = 0; d < 2; ++d)
            pacc[c * 2 + d] = fmaf(((const float*)&av[c])[kk],
                                   ((const float*)&wv[d])[kk], pacc[c * 2 + d]);
    }
#pragma unroll
    for (int p = 0; p < 16; ++p) acc[p] += pacc[p];
  }

  float* dst = ws +
      (ks == 0 ? (which ? OFF_B : OFF_A) : OFF_DOT + (which ? 4 * PLANE : 0)) +
      (size_t)r * PLANE;
#pragma unroll
  for (int c = 0; c < 8; ++c) {
    float2 v;
    v.x = acc[c * 2 + 0];
    v.y = acc[c * 2 + 1];
    *(float2*)(dst + (size_t)(i0 + ty + 16 * c) * 512 + h0 + 2 * tx) = v;
  }
}

// ---------------- K1: sum k-partials (+b1), center in place, stats, planes ----
__global__ __launch_bounds__(256) void k1_stats(float* __restrict__ ws,
                                                const float* __restrict__ gamma,
                                                const float* __restrict__ beta,
                                                const float* __restrict__ w2,
                                                const float* __restrict__ b1) {
  __shared__ float red[4];
  const int t = threadIdx.x;
  const int gw = (blockIdx.x * 256 + t) >> 6;
  const int lane = t & 63;
  const int which = gw >> 11, rr = (gw >> 9) & 3, row = gw & 511;
  float* base = ws + (which ? OFF_B : OFF_A) +
                (size_t)(rr * 512 + row) * 512 + lane * 8;
  const float* pbase = ws + OFF_DOT + (which ? 4 * PLANE : 0) +
                       (size_t)rr * PLANE + (size_t)row * 512 + lane * 8;
  float v[8];
#pragma unroll
  for (int c = 0; c < 2; ++c) {
    const float4 v1 = *(const float4*)(base + 4 * c);
    const float4 v2 = *(const float4*)(pbase + 4 * c);
    v[4 * c + 0] = v1.x + v2.x;
    v[4 * c + 1] = v1.y + v2.y;
    v[4 * c + 2] = v1.z + v2.z;
    v[4 * c + 3] = v1.w + v2.w;
  }
  if (which) {
#pragma unroll
    for (int c = 0; c < 2; ++c) {
      const float4 bb = *(const float4*)(b1 + rr * 512 + lane * 8 + 4 * c);
      v[4 * c + 0] += bb.x; v[4 * c + 1] += bb.y;
      v[4 * c + 2] += bb.z; v[4 * c + 3] += bb.w;
    }
  }
  float s = 0.f;
#pragma unroll
  for (int e = 0; e < 8; ++e) s += v[e];
#pragma unroll
  for (int off = 32; off >= 1; off >>= 1) s += __shfl_xor(s, off, 64);
  const float ma = s * (1.f / 512.f);

  const float* gp = gamma + rr * 512 + lane * 8;
  const float* wp = w2 + rr * 512 + lane * 8;
  float q = 0.f, pa = 0.f, cv[8];
#pragma unroll
  for (int c = 0; c < 2; ++c) {
    const float4 g = *(const float4*)(gp + 4 * c);
    const float4 w = *(const float4*)(wp + 4 * c);
    const float gv[4] = {g.x, g.y, g.z, g.w};
    const float wv[4] = {w.x, w.y, w.z, w.w};
#pragma unroll
    for (int e = 0; e < 4; ++e) {
      const float ce = v[4 * c + e] - ma;
      cv[4 * c + e] = ce;
      q += ce * ce;
      pa += 0.5f * gv[e] * wv[e] * ce;
    }
  }
#pragma unroll
  for (int c = 0; c < 2; ++c) {
    float4 o;
    o.x = cv[4 * c + 0]; o.y = cv[4 * c + 1];
    o.z = cv[4 * c + 2]; o.w = cv[4 * c + 3];
    *(float4*)(base + 4 * c) = o;
  }
#pragma unroll
  for (int off = 32; off >= 1; off >>= 1) {
    q += __shfl_down(q, off, 64);
    pa += __shfl_down(pa, off, 64);
  }
  if (lane == 0) {
    ws[(which ? OFF_QB : OFF_QA) + rr * 512 + row] = q;
    ws[(which ? OFF_PBp : OFF_PAp) + rr * 512 + row] = pa;
  }
  if (blockIdx.x < 8) {
    const int idx = blockIdx.x * 256 + t;  // r*512+k
    const float g = gamma[idx], be = beta[idx], w = w2[idx];
    const float qv = 0.5f * be * w;
    ws[OFF_P + idx] = 0.5f * g * w;
    ws[OFF_Q + idx] = qv;
    ws[OFF_SG + idx] = copysignf(1.f, w);
    float qs = qv;
#pragma unroll
    for (int off = 32; off >= 1; off >>= 1) qs += __shfl_down(qs, off, 64);
    if ((t & 63) == 0) red[t >> 6] = qs;
    __syncthreads();
    if (t == 0) ws[OFF_QSP + blockIdx.x] = red[0] + red[1] + red[2] + red[3];
  }
}

// ---------------- K2: pairwise dot on centered arrays ----------------
// grid 512 = 16jt(32) x 4it(128) x 4r x 2ks; block 256; Pi=8 (global), Pj=2 (LDS)
__global__ __launch_bounds__(256) void k2_dot(const float* __restrict__ wsA,
                                              const float* __restrict__ wsB,
                                              float* __restrict__ wsDot) {
  const int b = blockIdx.x;
  const int jt = b & 15, it = (b >> 4) & 3, r = (b >> 6) & 3, ks = b >> 8;
  const int i0 = it << 7, j0 = jt << 5, kb0 = ks << 8;
  const int t = threadIdx.x, tx = t & 15, ty = t >> 4;

  __shared__ float Bs[32 * 64];

  const float* ap[8];
#pragma unroll
  for (int c = 0; c < 8; ++c)
    ap[c] = wsA + (size_t)(r * 512 + i0 + ty + 16 * c) * 512 + kb0;
  const int brow = t >> 3, bcol = t & 7;
  const int swb = swz(brow);
  const float* bsrc = wsB + (size_t)(r * 512 + j0 + brow) * 512 + kb0;

  float acc[16];
#pragma unroll
  for (int p = 0; p < 16; ++p) acc[p] = 0.f;

  for (int kc = 0; kc < 4; ++kc) {
    const int ko = kc << 6;
    const float4 b0 = *(const float4*)(bsrc + ko + 4 * bcol);
    const float4 b1v = *(const float4*)(bsrc + ko + 4 * (bcol + 8));
    __syncthreads();
    *(float4*)&Bs[brow * 64 + ((bcol ^ swb) << 2)] = b0;
    *(float4*)&Bs[brow * 64 + (((bcol + 8) ^ swb) << 2)] = b1v;
    __syncthreads();
    float pacc[16];
#pragma unroll
    for (int p = 0; p < 16; ++p) pacc[p] = 0.f;
#pragma unroll 4
    for (int k4 = 0; k4 < 16; ++k4) {
      float4 av[8], bv[2];
#pragma unroll
      for (int c = 0; c < 8; ++c) av[c] = *(const float4*)(ap[c] + ko + 4 * k4);
#pragma unroll
      for (int d = 0; d < 2; ++d) {
        const int rw = 2 * tx + d;
        bv[d] = *(const float4*)&Bs[rw * 64 + ((k4 ^ swz(rw)) << 2)];
      }
#pragma unroll
      for (int kk = 0; kk < 4; ++kk)
#pragma unroll
        for (int c = 0; c < 8; ++c)
#pragma unroll
          for (int d = 0; d < 2; ++d)
            pacc[c * 2 + d] = fmaf(((const float*)&av[c])[kk],
                                   ((const float*)&bv[d])[kk], pacc[c * 2 + d]);
    }
#pragma unroll
    for (int p = 0; p < 16; ++p) acc[p] += pacc[p];
  }

  float* dst = wsDot + (size_t)ks * (4 * PLANE) + (size_t)r * PLANE;
#pragma unroll
  for (int c = 0; c < 8; ++c) {
    float2 v;
    v.x = acc[c * 2 + 0];
    v.y = acc[c * 2 + 1];
    *(float2*)(dst + (size_t)(i0 + ty + 16 * c) * 512 + j0 + 2 * tx) = v;
  }
}

// ---------------- K3: score kernel — 3-op inner loop ----------------
// grid 1024 = 16jt(32) x 8it(64) x 4r x 2ks; block 256 (16tx x 16ty; 4i x 2j)
// A~ from global (4-line broadcasts); B^=P*B~ staged in LDS; P/Q/S via s_load.
__global__ __launch_bounds__(256) void k3_score(const float* __restrict__ wsA,
                                                const float* __restrict__ wsB,
                                                const float* __restrict__ wsDot,
                                                const float* __restrict__ stats,
                                                const float* __restrict__ planes,
                                                float* __restrict__ sout) {
  const int b = blockIdx.x;
  const int jt = b & 15, it = (b >> 4) & 7, r = (b >> 7) & 3, ks = b >> 9;
  const int i0 = it << 6, j0 = jt << 5, kb0 = ks << 8;
  const int t = threadIdx.x, tx = t & 15, ty = t >> 4;

  __shared__ float Bh[32 * 64];   // 8 KB

  // stats base = ws+OFF_QA: QA +0, PAp +2048, QB +6144, PBp +8192
  const float4 qav = *(const float4*)(stats + 0 + r * 512 + i0 + 4 * ty);
  const float4 pav = *(const float4*)(stats + 2048 + r * 512 + i0 + 4 * ty);
  const float2 qbv = *(const float2*)(stats + 6144 + r * 512 + j0 + 2 * tx);
  const float2 pbv = *(const float2*)(stats + 8192 + r * 512 + j0 + 2 * tx);
  const float qaA[4] = {qav.x, qav.y, qav.z, qav.w};
  const float paA[4] = {pav.x, pav.y, pav.z, pav.w};
  const float qbA[2] = {qbv.x, qbv.y};
  const float pbA[2] = {pbv.x, pbv.y};

  float Sv[8], acc[8];
#pragma unroll
  for (int c = 0; c < 4; ++c) {
    const size_t doff =
        (size_t)r * PLANE + (size_t)(i0 + 4 * ty + c) * 512 + j0 + 2 * tx;
    const float2 d0 = *(const float2*)(wsDot + doff);
    const float2 d1 = *(const float2*)(wsDot + 4 * PLANE + doff);
    const float dA[2] = {d0.x + d1.x, d0.y + d1.y};
#pragma unroll
    for (int d = 0; d < 2; ++d) {
      const int p = c * 2 + d;
      const float var = (qaA[c] + qbA[d] + 2.f * dA[d]) * (1.f / 512.f);
      const float sv = 1.0f / sqrtf(var + 1e-5f);  // precise (no fast-math)
      Sv[p] = sv;
      acc[p] = ks ? 0.f : sv * (paA[c] + pbA[d]);  // linear half (ks==0 only)
    }
  }

  const float* ap[4];
#pragma unroll
  for (int c = 0; c < 4; ++c)
    ap[c] = wsA + (size_t)(r * 512 + i0 + 4 * ty + c) * 512 + kb0;
  const int brow = t >> 3, bcol = t & 7;
  const int swb = swz(brow);
  const float* bsrc = wsB + (size_t)(r * 512 + j0 + brow) * 512 + kb0;
  const float* pP = planes + r * 512 + kb0;  // P +0, Q +2048, SG +4096

  for (int kc = 0; kc < 4; ++kc) {
    const int ko = kc << 6;
    const float4 b0 = *(const float4*)(bsrc + ko + 4 * bcol);
    const float4 b1v = *(const float4*)(bsrc + ko + 4 * (bcol + 8));
    const float4 p0 = *(const float4*)(pP + ko + 4 * bcol);
    const float4 p1 = *(const float4*)(pP + ko + 4 * (bcol + 8));
    float4 h0, h1;
    h0.x = b0.x * p0.x; h0.y = b0.y * p0.y;
    h0.z = b0.z * p0.z; h0.w = b0.w * p0.w;
    h1.x = b1v.x * p1.x; h1.y = b1v.y * p1.y;
    h1.z = b1v.z * p1.z; h1.w = b1v.w * p1.w;
    __syncthreads();
    *(float4*)&Bh[brow * 64 + ((bcol ^ swb) << 2)] = h0;
    *(float4*)&Bh[brow * 64 + (((bcol + 8) ^ swb) << 2)] = h1;
    __syncthreads();

    float cacc[8];
#pragma unroll
    for (int p = 0; p < 8; ++p) cacc[p] = 0.f;
#pragma unroll 4
    for (int k4 = 0; k4 < 16; ++k4) {
      float4 av[4], bv[2];
#pragma unroll
      for (int c = 0; c < 4; ++c) av[c] = *(const float4*)(ap[c] + ko + 4 * k4);
#pragma unroll
      for (int d = 0; d < 2; ++d) {
        const int rw = 2 * tx + d;
        bv[d] = *(const float4*)&Bh[rw * 64 + ((k4 ^ swz(rw)) << 2)];
      }
      // wave-uniform -> scalar loads
      const float4 Pk = *(const float4*)(pP + ko + 4 * k4);
      const float4 Qk = *(const float4*)(pP + 2048 + ko + 4 * k4);
      const float4 Sk = *(const float4*)(pP + 4096 + ko + 4 * k4);
#pragma unroll
      for (int kk = 0; kk < 4; ++kk) {
        const float pk = ((const float*)&Pk)[kk];
        const float qk = ((const float*)&Qk)[kk];
        const float sk = ((const float*)&Sk)[kk];
        float aa[4], bb[2];
#pragma unroll
        for (int c = 0; c < 4; ++c) aa[c] = ((const float*)&av[c])[kk];
#pragma unroll
        for (int d = 0; d < 2; ++d) bb[d] = ((const float*)&bv[d])[kk];
#pragma unroll
        for (int c = 0; c < 4; ++c)
#pragma unroll
          for (int d = 0; d < 2; ++d) {
            const int p = c * 2 + d;
            const float u = fmaf(aa[c], pk, bb[d]);       // P*(a~+b~)
            const float h = fmaf(u, Sv[p], qk);           // sv*u + Q
            cacc[p] = fmaf(fabsf(h), sk, cacc[p]);        // abs = free modifier
          }
      }
    }
#pragma unroll
    for (int p = 0; p < 8; ++p) acc[p] += cacc[p];
  }

  float* dst = sout + (size_t)ks * (4 * PLANE) + (size_t)r * PLANE;
#pragma unroll
  for (int c = 0; c < 4; ++c) {
    float2 v;
    v.x = acc[c * 2 + 0];
    v.y = acc[c * 2 + 1];
    *(float2*)(dst + (size_t)(i0 + 4 * ty + c) * 512 + j0 + 2 * tx) = v;
  }
}

// ---------------- K4: combine + outputs ----------------
__global__ __launch_bounds__(256) void k4_combine(const float* __restrict__ ws,
                                                  const float* __restrict__ img,
                                                  const float* __restrict__ txt,
                                                  const float* __restrict__ b2,
                                                  float* __restrict__ out) {
  const int idx = blockIdx.x * 256 + threadIdx.x;
  const int i = idx >> 9, j = idx & 511;
  const float* s0 = ws + OFF_S;
  const float* s1 = ws + OFF_S + 4 * PLANE;
  const float* qsp = ws + OFF_QSP;
  float best = -3.4e38f;
  int rel = 0;
#pragma unroll
  for (int r = 0; r < 4; ++r) {
    const float cr = b2[r] + qsp[2 * r] + qsp[2 * r + 1];
    const float s = s0[r * PLANE + idx] + s1[r * PLANE + idx] + cr;
    if (s > best) { best = s; rel = r; }  // strict > == first-index argmax
  }
  out[idx] = (i < 256) ? img[idx] : txt[idx - 131072];
  out[PLANE + idx] = best;
  out[2 * PLANE + idx] = (float)rel;
  out[3 * PLANE + idx] = (i != j && (double)best > 0.2) ? 1.0f : 0.0f;
}

extern "C" void kernel_launch(void* const* d_in, const int* in_sizes, int n_in,
                              void* d_out, int out_size, void* d_ws, size_t ws_size,
                              hipStream_t stream) {
  const float* img   = (const float*)d_in[0];
  const float* txt   = (const float*)d_in[1];
  const float* W1    = (const float*)d_in[2];
  const float* b1    = (const float*)d_in[3];
  const float* gamma = (const float*)d_in[4];
  const float* beta  = (const float*)d_in[5];
  const float* w2    = (const float*)d_in[6];
  const float* b2    = (const float*)d_in[7];
  float* ws  = (float*)d_ws;
  float* out = (float*)d_out;
  (void)in_sizes; (void)n_in; (void)out_size; (void)ws_size;

  hipLaunchKernelGGL(k0_gemm,    dim3(1024), dim3(256), 0, stream, img, txt, W1, ws);
  hipLaunchKernelGGL(k1_stats,   dim3(1024), dim3(256), 0, stream, ws, gamma, beta, w2, b1);
  hipLaunchKernelGGL(k2_dot,     dim3(512),  dim3(256), 0, stream,
                     ws + OFF_A, ws + OFF_B, ws + OFF_DOT);
  hipLaunchKernelGGL(k3_score,   dim3(1024), dim3(256), 0, stream,
                     ws + OFF_A, ws + OFF_B, ws + OFF_DOT,
                     ws + OFF_QA, ws + OFF_P, ws + OFF_S);
  hipLaunchKernelGGL(k4_combine, dim3(1024), dim3(256), 0, stream, ws, img, txt, b2, out);
}

// Round 6
// 200.553 us; speedup vs baseline: 1.9308x; 1.2260x over previous
//
#include <hip/hip_runtime.h>
#include <math.h>

// DynamicRelationModeler — R6.
// Exact decomposition: relu(z)=(z+|z|)/2; P=w2*gamma/2, Q=w2*beta/2, S=sign(w2):
//   score = sv*(PA'_i+PB'_j) + QS_r + b2_r + sum_k S_k*|sv*P_k*(a~+b~) + Q_k|
// a~,b~ centered by K1 (b1 folded); sv = rsqrt((Qa_i + Qb_j + 2*dot_ij)/512 + eps).
// Placement rules (calibrated R1/R5): broadcast global load ~12 cyc TA; LDS
// k-major contiguous-256B read ~3-4 cyc; strided 16-row LDS b128 ~12 cyc.
// So: tx-side operands staged k-major in LDS; ty-side either 4-line global
// broadcast (K3) or k-major LDS (K0/K2); P/Q/S wave-uniform s_load.

namespace {
constexpr size_t PLANE   = 512 * 512;
constexpr size_t OFF_A   = 0;               // [4][512][512] centered a~
constexpr size_t OFF_B   = 4 * PLANE;       // [4][512][512] centered b~
constexpr size_t OFF_DOT = 8 * PLANE;       // 16 planes: K0 ks=1 partials (first 8), then K2 dot[4ks][4r]
constexpr size_t OFF_S   = 24 * PLANE;      // 16 planes: Spart[4ks][4r]
constexpr size_t OFF_QA  = 40 * PLANE;      // stats block (contig): QA,PAp,QB,PBp
constexpr size_t OFF_PAp = OFF_QA + 2048;
constexpr size_t OFF_QB  = OFF_QA + 4096;
constexpr size_t OFF_PBp = OFF_QA + 6144;
constexpr size_t OFF_P   = OFF_QA + 8192;   // planes (contig): P,Q,SG
constexpr size_t OFF_Q   = OFF_QA + 10240;
constexpr size_t OFF_SG  = OFF_QA + 12288;
constexpr size_t OFF_QSP = OFF_QA + 14336;  // 8 floats
}

// ---------------- K0: input GEMM  [512 i]x[2which*4r*512h], k-split x2 -------
// grid 512 = 4it(128) x 2which x 4r x 8ht(64) x 2ks(256k); block 256 (16tx x 16ty)
// Pi=8 (i = i0 + {0,64} + 4ty+c), Pj=4 (h = h0+4tx+d); both operands LDS k-major.
__global__ __launch_bounds__(256, 2) void k0_gemm(const float* __restrict__ img,
                                                  const float* __restrict__ txt,
                                                  const float* __restrict__ W1,
                                                  float* __restrict__ ws) {
  const int b = blockIdx.x;
  const int ks = b & 1, ht = (b >> 1) & 7, r = (b >> 4) & 3;
  const int which = (b >> 6) & 1, it = b >> 7;
  const int i0 = it << 7, h0 = ht << 6, kb0 = ks << 8;
  const int t = threadIdx.x, tx = t & 15, ty = t >> 4;

  __shared__ float Xl[64 * 128];  // [k][i] 32 KB
  __shared__ float Wl[64 * 64];   // [k][h] 16 KB

  const int xi = i0 + (t & 127);
  const float* xrow = (xi < 256 ? img + (size_t)xi * 512
                                : txt + (size_t)(xi - 256) * 512) + kb0;
  const int xcg = t >> 7;  // 0..1
  const float* wrow =
      W1 + (size_t)(r * 512 + h0 + (t & 63)) * 1024 + which * 512 + kb0;
  const int wcg = t >> 6;  // 0..3

  float acc[32];
#pragma unroll
  for (int p = 0; p < 32; ++p) acc[p] = 0.f;

  for (int kh = 0; kh < 4; ++kh) {  // 4 stages of 64 k
    const int kb = kh << 6;
    float4 xv[8], wv4[4];
#pragma unroll
    for (int m = 0; m < 8; ++m)
      xv[m] = *(const float4*)(xrow + kb + 4 * (xcg + 2 * m));
#pragma unroll
    for (int m = 0; m < 4; ++m)
      wv4[m] = *(const float4*)(wrow + kb + 4 * (wcg + 4 * m));
    __syncthreads();
#pragma unroll
    for (int m = 0; m < 8; ++m) {
      const int c = xcg + 2 * m;
      Xl[(4 * c + 0) * 128 + (t & 127)] = xv[m].x;
      Xl[(4 * c + 1) * 128 + (t & 127)] = xv[m].y;
      Xl[(4 * c + 2) * 128 + (t & 127)] = xv[m].z;
      Xl[(4 * c + 3) * 128 + (t & 127)] = xv[m].w;
    }
#pragma unroll
    for (int m = 0; m < 4; ++m) {
      const int c = wcg + 4 * m;
      Wl[(4 * c + 0) * 64 + (t & 63)] = wv4[m].x;
      Wl[(4 * c + 1) * 64 + (t & 63)] = wv4[m].y;
      Wl[(4 * c + 2) * 64 + (t & 63)] = wv4[m].z;
      Wl[(4 * c + 3) * 64 + (t & 63)] = wv4[m].w;
    }
    __syncthreads();
#pragma unroll 4
    for (int kq = 0; kq < 64; ++kq) {
      const float4 a1 = *(const float4*)(Xl + kq * 128 + 4 * ty);
      const float4 a2 = *(const float4*)(Xl + kq * 128 + 64 + 4 * ty);
      const float4 w = *(const float4*)(Wl + kq * 64 + 4 * tx);
      const float a1A[4] = {a1.x, a1.y, a1.z, a1.w};
      const float a2A[4] = {a2.x, a2.y, a2.z, a2.w};
      const float wA[4] = {w.x, w.y, w.z, w.w};
#pragma unroll
      for (int c = 0; c < 4; ++c)
#pragma unroll
        for (int d = 0; d < 4; ++d) {
          acc[c * 4 + d] = fmaf(a1A[c], wA[d], acc[c * 4 + d]);
          acc[16 + c * 4 + d] = fmaf(a2A[c], wA[d], acc[16 + c * 4 + d]);
        }
    }
  }

  float* base = (ks == 0)
      ? ws + (which ? OFF_B : OFF_A) + (size_t)r * PLANE
      : ws + OFF_DOT + (size_t)which * 4 * PLANE + (size_t)r * PLANE;
#pragma unroll
  for (int g = 0; g < 2; ++g)
#pragma unroll
    for (int c = 0; c < 4; ++c) {
      float4 v;
      v.x = acc[g * 16 + c * 4 + 0];
      v.y = acc[g * 16 + c * 4 + 1];
      v.z = acc[g * 16 + c * 4 + 2];
      v.w = acc[g * 16 + c * 4 + 3];
      *(float4*)(base + (size_t)(i0 + 64 * g + 4 * ty + c) * 512 + h0 + 4 * tx) = v;
    }
}

// ---------------- K1: sum k-partials (+b1), center in place, stats, planes ----
__global__ __launch_bounds__(256) void k1_stats(float* __restrict__ ws,
                                                const float* __restrict__ gamma,
                                                const float* __restrict__ beta,
                                                const float* __restrict__ w2,
                                                const float* __restrict__ b1) {
  __shared__ float red[4];
  const int t = threadIdx.x;
  const int gw = (blockIdx.x * 256 + t) >> 6;
  const int lane = t & 63;
  const int which = gw >> 11, rr = (gw >> 9) & 3, row = gw & 511;
  float* base = ws + (which ? OFF_B : OFF_A) +
                (size_t)(rr * 512 + row) * 512 + lane * 8;
  const float* pbase = ws + OFF_DOT + (size_t)which * 4 * PLANE +
                       (size_t)rr * PLANE + (size_t)row * 512 + lane * 8;
  float v[8];
#pragma unroll
  for (int c = 0; c < 2; ++c) {
    const float4 v1 = *(const float4*)(base + 4 * c);
    const float4 v2 = *(const float4*)(pbase + 4 * c);
    v[4 * c + 0] = v1.x + v2.x;
    v[4 * c + 1] = v1.y + v2.y;
    v[4 * c + 2] = v1.z + v2.z;
    v[4 * c + 3] = v1.w + v2.w;
  }
  if (which) {
#pragma unroll
    for (int c = 0; c < 2; ++c) {
      const float4 bb = *(const float4*)(b1 + rr * 512 + lane * 8 + 4 * c);
      v[4 * c + 0] += bb.x; v[4 * c + 1] += bb.y;
      v[4 * c + 2] += bb.z; v[4 * c + 3] += bb.w;
    }
  }
  float s = 0.f;
#pragma unroll
  for (int e = 0; e < 8; ++e) s += v[e];
#pragma unroll
  for (int off = 32; off >= 1; off >>= 1) s += __shfl_xor(s, off, 64);
  const float ma = s * (1.f / 512.f);

  const float* gp = gamma + rr * 512 + lane * 8;
  const float* wp = w2 + rr * 512 + lane * 8;
  float q = 0.f, pa = 0.f, cv[8];
#pragma unroll
  for (int c = 0; c < 2; ++c) {
    const float4 g = *(const float4*)(gp + 4 * c);
    const float4 w = *(const float4*)(wp + 4 * c);
    const float gv[4] = {g.x, g.y, g.z, g.w};
    const float wv[4] = {w.x, w.y, w.z, w.w};
#pragma unroll
    for (int e = 0; e < 4; ++e) {
      const float ce = v[4 * c + e] - ma;
      cv[4 * c + e] = ce;
      q += ce * ce;
      pa += 0.5f * gv[e] * wv[e] * ce;
    }
  }
#pragma unroll
  for (int c = 0; c < 2; ++c) {
    float4 o;
    o.x = cv[4 * c + 0]; o.y = cv[4 * c + 1];
    o.z = cv[4 * c + 2]; o.w = cv[4 * c + 3];
    *(float4*)(base + 4 * c) = o;
  }
#pragma unroll
  for (int off = 32; off >= 1; off >>= 1) {
    q += __shfl_down(q, off, 64);
    pa += __shfl_down(pa, off, 64);
  }
  if (lane == 0) {
    ws[(which ? OFF_QB : OFF_QA) + rr * 512 + row] = q;
    ws[(which ? OFF_PBp : OFF_PAp) + rr * 512 + row] = pa;
  }
  if (blockIdx.x < 8) {
    const int idx = blockIdx.x * 256 + t;  // r*512+k
    const float g = gamma[idx], be = beta[idx], w = w2[idx];
    const float qv = 0.5f * be * w;
    ws[OFF_P + idx] = 0.5f * g * w;
    ws[OFF_Q + idx] = qv;
    ws[OFF_SG + idx] = copysignf(1.f, w);
    float qs = qv;
#pragma unroll
    for (int off = 32; off >= 1; off >>= 1) qs += __shfl_down(qs, off, 64);
    if ((t & 63) == 0) red[t >> 6] = qs;
    __syncthreads();
    if (t == 0) ws[OFF_QSP + blockIdx.x] = red[0] + red[1] + red[2] + red[3];
  }
}

// ---------------- K2: pairwise dot, k-split x4 ----------------
// grid 512 = 4it(128) x 8jt(64) x 4r x 4ks(128k); block 256; both operands LDS k-major.
__global__ __launch_bounds__(256, 2) void k2_dot(const float* __restrict__ wsA,
                                                 const float* __restrict__ wsB,
                                                 float* __restrict__ wsDot) {
  const int b = blockIdx.x;
  const int ks = b & 3, r = (b >> 2) & 3, jt = (b >> 4) & 7, it = b >> 7;
  const int i0 = it << 7, j0 = jt << 6, kb0 = ks << 7;
  const int t = threadIdx.x, tx = t & 15, ty = t >> 4;

  __shared__ float Al[64 * 128];  // [k][i] 32 KB
  __shared__ float Bl[64 * 64];   // [k][j] 16 KB

  const float* arow = wsA + (size_t)(r * 512 + i0 + (t & 127)) * 512 + kb0;
  const int acg = t >> 7;  // 0..1
  const float* brow = wsB + (size_t)(r * 512 + j0 + (t & 63)) * 512 + kb0;
  const int bcg = t >> 6;  // 0..3

  float acc[32];
#pragma unroll
  for (int p = 0; p < 32; ++p) acc[p] = 0.f;

  for (int kh = 0; kh < 2; ++kh) {  // 2 stages of 64 k
    const int kb = kh << 6;
    float4 av4[8], bv4[4];
#pragma unroll
    for (int m = 0; m < 8; ++m)
      av4[m] = *(const float4*)(arow + kb + 4 * (acg + 2 * m));
#pragma unroll
    for (int m = 0; m < 4; ++m)
      bv4[m] = *(const float4*)(brow + kb + 4 * (bcg + 4 * m));
    __syncthreads();
#pragma unroll
    for (int m = 0; m < 8; ++m) {
      const int c = acg + 2 * m;
      Al[(4 * c + 0) * 128 + (t & 127)] = av4[m].x;
      Al[(4 * c + 1) * 128 + (t & 127)] = av4[m].y;
      Al[(4 * c + 2) * 128 + (t & 127)] = av4[m].z;
      Al[(4 * c + 3) * 128 + (t & 127)] = av4[m].w;
    }
#pragma unroll
    for (int m = 0; m < 4; ++m) {
      const int c = bcg + 4 * m;
      Bl[(4 * c + 0) * 64 + (t & 63)] = bv4[m].x;
      Bl[(4 * c + 1) * 64 + (t & 63)] = bv4[m].y;
      Bl[(4 * c + 2) * 64 + (t & 63)] = bv4[m].z;
      Bl[(4 * c + 3) * 64 + (t & 63)] = bv4[m].w;
    }
    __syncthreads();
#pragma unroll 4
    for (int kq = 0; kq < 64; ++kq) {
      const float4 a1 = *(const float4*)(Al + kq * 128 + 4 * ty);
      const float4 a2 = *(const float4*)(Al + kq * 128 + 64 + 4 * ty);
      const float4 bq = *(const float4*)(Bl + kq * 64 + 4 * tx);
      const float a1A[4] = {a1.x, a1.y, a1.z, a1.w};
      const float a2A[4] = {a2.x, a2.y, a2.z, a2.w};
      const float bA[4] = {bq.x, bq.y, bq.z, bq.w};
#pragma unroll
      for (int c = 0; c < 4; ++c)
#pragma unroll
        for (int d = 0; d < 4; ++d) {
          acc[c * 4 + d] = fmaf(a1A[c], bA[d], acc[c * 4 + d]);
          acc[16 + c * 4 + d] = fmaf(a2A[c], bA[d], acc[16 + c * 4 + d]);
        }
    }
  }

  float* dst = wsDot + (size_t)(ks * 4 + r) * PLANE;
#pragma unroll
  for (int g = 0; g < 2; ++g)
#pragma unroll
    for (int c = 0; c < 4; ++c) {
      float4 v;
      v.x = acc[g * 16 + c * 4 + 0];
      v.y = acc[g * 16 + c * 4 + 1];
      v.z = acc[g * 16 + c * 4 + 2];
      v.w = acc[g * 16 + c * 4 + 3];
      *(float4*)(dst + (size_t)(i0 + 64 * g + 4 * ty + c) * 512 + j0 + 4 * tx) = v;
    }
}

// ---------------- K3: score kernel — 3-op inner loop, k-split x4 ----------------
// grid 512 = 4it(128) x 8jt(64) x 4r x 4ks(128k); block 512 (16tx x 32ty; 4i x 4j)
// -> 2 blocks/CU, 16 waves/CU. a~ global (4-line broadcast); B^=P*b~ LDS k-major;
// P/Q/S wave-uniform s_load.
__global__ __launch_bounds__(512, 4) void k3_score(const float* __restrict__ wsA,
                                                   const float* __restrict__ wsB,
                                                   const float* __restrict__ wsDot,
                                                   const float* __restrict__ stats,
                                                   const float* __restrict__ planes,
                                                   float* __restrict__ sout) {
  const int b = blockIdx.x;
  const int ks = b & 3, r = (b >> 2) & 3, jt = (b >> 4) & 7, it = b >> 7;
  const int i0 = it << 7, j0 = jt << 6, kb0 = ks << 7;
  const int t = threadIdx.x, tx = t & 15, ty = t >> 4;  // ty 0..31

  __shared__ float Bh[64 * 64];  // [k][j] 16 KB, holds P*b~ for 64-k stage

  // stats: QA +0, PAp +2048, QB +4096, PBp +6144
  const float4 qav = *(const float4*)(stats + 0 + r * 512 + i0 + 4 * ty);
  const float4 pav = *(const float4*)(stats + 2048 + r * 512 + i0 + 4 * ty);
  const float4 qbv = *(const float4*)(stats + 4096 + r * 512 + j0 + 4 * tx);
  const float4 pbv = *(const float4*)(stats + 6144 + r * 512 + j0 + 4 * tx);
  const float qaA[4] = {qav.x, qav.y, qav.z, qav.w};
  const float paA[4] = {pav.x, pav.y, pav.z, pav.w};
  const float qbA[4] = {qbv.x, qbv.y, qbv.z, qbv.w};
  const float pbA[4] = {pbv.x, pbv.y, pbv.z, pbv.w};

  float Sv[16], acc[16];
#pragma unroll
  for (int c = 0; c < 4; ++c) {
    float4 ds = make_float4(0.f, 0.f, 0.f, 0.f);
#pragma unroll
    for (int s2 = 0; s2 < 4; ++s2) {
      const float4 dv = *(const float4*)(wsDot + (size_t)(s2 * 4 + r) * PLANE +
                          (size_t)(i0 + 4 * ty + c) * 512 + j0 + 4 * tx);
      ds.x += dv.x; ds.y += dv.y; ds.z += dv.z; ds.w += dv.w;
    }
    const float dA[4] = {ds.x, ds.y, ds.z, ds.w};
#pragma unroll
    for (int d = 0; d < 4; ++d) {
      const int p = c * 4 + d;
      const float var = (qaA[c] + qbA[d] + 2.f * dA[d]) * (1.f / 512.f);
      const float sv = 1.0f / sqrtf(var + 1e-5f);  // precise (no fast-math)
      Sv[p] = sv;
      acc[p] = (ks == 0) ? sv * (paA[c] + pbA[d]) : 0.f;  // linear half once
    }
  }

  const float* ap[4];
#pragma unroll
  for (int c = 0; c < 4; ++c)
    ap[c] = wsA + (size_t)(r * 512 + i0 + 4 * ty + c) * 512 + kb0;
  const int sj = t & 63, scg = t >> 6;  // staging: row j, chunk group 0..7
  const float* bsrc = wsB + (size_t)(r * 512 + j0 + sj) * 512 + kb0;
  const float* pP = planes + r * 512 + kb0;  // P +0, Q +2048, SG +4096 (uniform)

  for (int kh = 0; kh < 2; ++kh) {  // 2 stages of 64 k
    const int kb = kh << 6;
    float4 sb[2], sp[2];
#pragma unroll
    for (int m = 0; m < 2; ++m) {
      const int c = scg + 8 * m;
      sb[m] = *(const float4*)(bsrc + kb + 4 * c);
      sp[m] = *(const float4*)(pP + kb + 4 * c);
    }
    __syncthreads();
#pragma unroll
    for (int m = 0; m < 2; ++m) {
      const int c = scg + 8 * m;
      Bh[(4 * c + 0) * 64 + sj] = sb[m].x * sp[m].x;
      Bh[(4 * c + 1) * 64 + sj] = sb[m].y * sp[m].y;
      Bh[(4 * c + 2) * 64 + sj] = sb[m].z * sp[m].z;
      Bh[(4 * c + 3) * 64 + sj] = sb[m].w * sp[m].w;
    }
    __syncthreads();

#pragma unroll 2
    for (int k4 = 0; k4 < 16; ++k4) {
      float4 av[4];
#pragma unroll
      for (int c = 0; c < 4; ++c)
        av[c] = *(const float4*)(ap[c] + kb + 4 * k4);
      const float4 Pk = *(const float4*)(pP + kb + 4 * k4);
      const float4 Qk = *(const float4*)(pP + 2048 + kb + 4 * k4);
      const float4 Sk = *(const float4*)(pP + 4096 + kb + 4 * k4);
#pragma unroll
      for (int kk = 0; kk < 4; ++kk) {
        const float4 bv = *(const float4*)(Bh + (4 * k4 + kk) * 64 + 4 * tx);
        const float bA[4] = {bv.x, bv.y, bv.z, bv.w};
        const float pk = ((const float*)&Pk)[kk];
        const float qk = ((const float*)&Qk)[kk];
        const float sk = ((const float*)&Sk)[kk];
#pragma unroll
        for (int c = 0; c < 4; ++c) {
          const float a = ((const float*)&av[c])[kk];
#pragma unroll
          for (int d = 0; d < 4; ++d) {
            const int p = c * 4 + d;
            const float u = fmaf(a, pk, bA[d]);   // P*(a~+b~)
            const float h = fmaf(u, Sv[p], qk);   // sv*u + Q
            acc[p] = fmaf(fabsf(h), sk, acc[p]);  // abs = free VOP3 modifier
          }
        }
      }
    }
  }

  float* dst = sout + (size_t)(ks * 4 + r) * PLANE;
#pragma unroll
  for (int c = 0; c < 4; ++c) {
    float4 v;
    v.x = acc[c * 4 + 0];
    v.y = acc[c * 4 + 1];
    v.z = acc[c * 4 + 2];
    v.w = acc[c * 4 + 3];
    *(float4*)(dst + (size_t)(i0 + 4 * ty + c) * 512 + j0 + 4 * tx) = v;
  }
}

// ---------------- K4: combine + outputs ----------------
__global__ __launch_bounds__(256) void k4_combine(const float* __restrict__ ws,
                                                  const float* __restrict__ img,
                                                  const float* __restrict__ txt,
                                                  const float* __restrict__ b2,
                                                  float* __restrict__ out) {
  const int idx = blockIdx.x * 256 + threadIdx.x;
  const int i = idx >> 9, j = idx & 511;
  const float* sp = ws + OFF_S;
  const float* qsp = ws + OFF_QSP;
  float best = -3.4e38f;
  int rel = 0;
#pragma unroll
  for (int r = 0; r < 4; ++r) {
    float s = b2[r] + qsp[2 * r] + qsp[2 * r + 1];
#pragma unroll
    for (int s2 = 0; s2 < 4; ++s2)
      s += sp[(size_t)(s2 * 4 + r) * PLANE + idx];
    if (s > best) { best = s; rel = r; }  // strict > == first-index argmax
  }
  out[idx] = (i < 256) ? img[idx] : txt[idx - 131072];
  out[PLANE + idx] = best;
  out[2 * PLANE + idx] = (float)rel;
  out[3 * PLANE + idx] = (i != j && (double)best > 0.2) ? 1.0f : 0.0f;
}

extern "C" void kernel_launch(void* const* d_in, const int* in_sizes, int n_in,
                              void* d_out, int out_size, void* d_ws, size_t ws_size,
                              hipStream_t stream) {
  const float* img   = (const float*)d_in[0];
  const float* txt   = (const float*)d_in[1];
  const float* W1    = (const float*)d_in[2];
  const float* b1    = (const float*)d_in[3];
  const float* gamma = (const float*)d_in[4];
  const float* beta  = (const float*)d_in[5];
  const float* w2    = (const float*)d_in[6];
  const float* b2    = (const float*)d_in[7];
  float* ws  = (float*)d_ws;
  float* out = (float*)d_out;
  (void)in_sizes; (void)n_in; (void)out_size; (void)ws_size;

  hipLaunchKernelGGL(k0_gemm,    dim3(512),  dim3(256), 0, stream, img, txt, W1, ws);
  hipLaunchKernelGGL(k1_stats,   dim3(1024), dim3(256), 0, stream, ws, gamma, beta, w2, b1);
  hipLaunchKernelGGL(k2_dot,     dim3(512),  dim3(256), 0, stream,
                     ws + OFF_A, ws + OFF_B, ws + OFF_DOT);
  hipLaunchKernelGGL(k3_score,   dim3(512),  dim3(512), 0, stream,
                     ws + OFF_A, ws + OFF_B, ws + OFF_DOT,
                     ws + OFF_QA, ws + OFF_P, ws + OFF_S);
  hipLaunchKernelGGL(k4_combine, dim3(1024), dim3(256), 0, stream, ws, img, txt, b2, out);
}